// Round 7
// baseline (367.751 us; speedup 1.0000x reference)
//
#include <hip/hip_runtime.h>
#include <stdint.h>

#define B_ 8
#define N_ 8192
#define S_ 2048
#define C1_ 128
#define C2_ 256
#define IN_ 384
#define H1_ 256
#define H2_ 128
#define M_ (B_*N_)   // 65536 rows

typedef short bf16x8 __attribute__((ext_vector_type(8)));
typedef float f32x4 __attribute__((ext_vector_type(4)));

__device__ __forceinline__ float bf2f(unsigned short s){
  union { unsigned int u; float f; } x; x.u = ((unsigned int)s) << 16; return x.f;
}
__device__ __forceinline__ unsigned short f2bf(float f){
  union { float f; unsigned int u; } x; x.f = f;
  unsigned int u = x.u;
  unsigned int r = (u + 0x7FFFu + ((u >> 16) & 1u)) >> 16;
  return (unsigned short)r;
}

// ---------------- prep: convert weights to bf16, zero stats ----------------
__global__ __launch_bounds__(256) void prep_kernel(const float* W1, const float* W2,
                                                   unsigned short* w1b, unsigned short* w2b,
                                                   float* stats){
  int i = blockIdx.x * 256 + threadIdx.x;
  if (i < 256*384) w1b[i] = f2bf(W1[i]);
  if (i < 128*256) w2b[i] = f2bf(W2[i]);
  if (i < 1536)    stats[i] = 0.f;
}

// ---------------- transpose [B][R][L] f32 -> out[b*L + l][stride] bf16 at col_off+r --------
__global__ __launch_bounds__(256) void transpose_kernel(const float* in, unsigned short* out,
                                                        int rows_in, int cols_in,
                                                        int out_stride, int out_col_off){
  __shared__ float tile[32][33];
  int b  = blockIdx.z;
  int l0 = blockIdx.x * 32, r0 = blockIdx.y * 32;
  int tx = threadIdx.x & 31, ty = threadIdx.x >> 5;
  const float* src = in + (size_t)b * rows_in * cols_in;
  #pragma unroll
  for (int rr = ty; rr < 32; rr += 8)
    tile[rr][tx] = src[(size_t)(r0 + rr) * cols_in + l0 + tx];
  __syncthreads();
  unsigned short* dst = out + (size_t)b * cols_in * out_stride;
  #pragma unroll
  for (int rr = ty; rr < 32; rr += 8)
    dst[(size_t)(l0 + rr) * out_stride + out_col_off + r0 + tx] = f2bf(tile[tx][rr]);
}

// ---------------- KNN pass 1: packed-key top-3 per S-piece, exact-recompute tail ----------
#define PIECES_ 8
#define SPP_ (S_ / PIECES_)   // 256 -> local idx fits 8 bits

__device__ __forceinline__ void insert_k(float& k0, float& k1, float& k2, float x){
  k2 = __builtin_amdgcn_fmed3f(k1, k2, x);
  k1 = __builtin_amdgcn_fmed3f(k0, k1, x);
  k0 = fminf(k0, x);
}

__device__ __forceinline__ void insert3(float& d0, float& d1, float& d2,
                                        int& i0, int& i1, int& i2,
                                        float x, int s){
  bool b0 = x < d0, b1 = x < d1, b2 = x < d2;
  i2 = b1 ? i1 : (b2 ? s : i2);        // index updates read pre-update state
  i1 = b0 ? i0 : (b1 ? s : i1);
  i0 = b0 ? s : i0;
  d2 = __builtin_amdgcn_fmed3f(d1, d2, x);   // uses old d1
  d1 = __builtin_amdgcn_fmed3f(d0, d1, x);   // uses old d0,d1
  d0 = fminf(d0, x);
}

__global__ __launch_bounds__(256, 8) void knn_kernel(const float* xyz1, const float* xyz2,
                                                     float* partd, int* parti){
  __shared__ float4 pts[SPP_];   // 4 KB
  int b = blockIdx.y, piece = blockIdx.z;
  int n = blockIdx.x * 256 + threadIdx.x;
  int base = piece * SPP_;
  const float* x2 = xyz2 + (size_t)b * 3 * S_;
  {
    int i = threadIdx.x;   // SPP_ == blockDim.x
    float px = x2[base + i], py = x2[S_ + base + i], pz = x2[2*S_ + base + i];
    pts[i] = make_float4(-2.f*px, -2.f*py, -2.f*pz, px*px + py*py + pz*pz);
  }
  __syncthreads();
  const float* x1 = xyz1 + (size_t)b * 3 * N_;
  float ax = x1[n], ay = x1[N_ + n], az = x1[2*N_ + n];
  float x1sq = ax*ax + ay*ay + az*az;

  const float KINIT = __uint_as_float(0x7F000000u);   // ~1.7e38, idx bits 0
  float k[2][3];
  k[0][0]=k[0][1]=k[0][2]=KINIT;
  k[1][0]=k[1][1]=k[1][2]=KINIT;

  for (int s = 0; s < SPP_; s += 8){
    #pragma unroll
    for (int u = 0; u < 8; u++){
      float4 c = pts[s + u];
      float dd = fmaf(ax, c.x, fmaf(ay, c.y, fmaf(az, c.z, c.w + x1sq)));
      dd = fmaxf(dd, 0.f);
      float key = __uint_as_float((__float_as_uint(dd) & 0xFFFFFF00u) | (unsigned)(s + u));
      int L = u & 1;
      insert_k(k[L][0], k[L][1], k[L][2], key);
    }
  }
  float e0 = k[0][0], e1 = k[0][1], e2 = k[0][2];
  insert_k(e0, e1, e2, k[1][0]);
  insert_k(e0, e1, e2, k[1][1]);
  insert_k(e0, e1, e2, k[1][2]);

  // decode winners, recompute exact distances from LDS
  float ed[3]; int ei[3];
  float ev[3] = {e0, e1, e2};
  #pragma unroll
  for (int j = 0; j < 3; j++){
    int li = (int)(__float_as_uint(ev[j]) & 0xFFu);
    float4 c = pts[li];
    float dd = fmaf(ax, c.x, fmaf(ay, c.y, fmaf(az, c.z, c.w + x1sq)));
    ed[j] = fmaxf(dd, 0.f);
    ei[j] = base + li;
  }

  size_t g = (size_t)b * N_ + n;
  partd[(piece*3 + 0)*(size_t)M_ + g] = ed[0];
  partd[(piece*3 + 1)*(size_t)M_ + g] = ed[1];
  partd[(piece*3 + 2)*(size_t)M_ + g] = ed[2];
  parti[(piece*3 + 0)*(size_t)M_ + g] = ei[0];
  parti[(piece*3 + 1)*(size_t)M_ + g] = ei[1];
  parti[(piece*3 + 2)*(size_t)M_ + g] = ei[2];
}

// pass 2: exact merge of 8 pieces' top-3 (already true-distance space), weights
__global__ __launch_bounds__(256) void knn_merge_kernel(const float* partd, const int* parti,
                                                        int* idx, float* wgt){
  size_t g = (size_t)blockIdx.x * 256 + threadIdx.x;
  float d0 = partd[0*(size_t)M_ + g], d1 = partd[1*(size_t)M_ + g], d2 = partd[2*(size_t)M_ + g];
  int   i0 = parti[0*(size_t)M_ + g], i1 = parti[1*(size_t)M_ + g], i2 = parti[2*(size_t)M_ + g];
  #pragma unroll
  for (int p = 1; p < PIECES_; p++)
    #pragma unroll
    for (int j = 0; j < 3; j++)
      insert3(d0, d1, d2, i0, i1, i2,
              partd[(p*3 + j)*(size_t)M_ + g], parti[(p*3 + j)*(size_t)M_ + g]);

  float r0 = 1.f/(d0 + 1e-8f), r1 = 1.f/(d1 + 1e-8f), r2 = 1.f/(d2 + 1e-8f);
  float rs = 1.f/(r0 + r1 + r2);
  idx[g*3+0] = i0; idx[g*3+1] = i1; idx[g*3+2] = i2;
  wgt[g*3+0] = r0*rs; wgt[g*3+1] = r1*rs; wgt[g*3+2] = r2*rs;
}

// ---------------- gather + weighted interp into x[:,128:384] ----------------
__global__ __launch_bounds__(256) void interp_kernel(const int* idx, const float* wgt,
                                                     const unsigned short* p2t, unsigned short* x){
  int t = threadIdx.x;                 // channel 0..255
  int base = blockIdx.x * 16;
  for (int k = 0; k < 16; k++){
    int g = base + k;
    int b = g >> 13;
    const int*   ip = idx + (size_t)g * 3;
    const float* wp = wgt + (size_t)g * 3;
    const unsigned short* p = p2t + (size_t)b * S_ * C2_;
    float v = wp[0]*bf2f(p[(size_t)ip[0]*C2_ + t])
            + wp[1]*bf2f(p[(size_t)ip[1]*C2_ + t])
            + wp[2]*bf2f(p[(size_t)ip[2]*C2_ + t]);
    x[(size_t)g * IN_ + C1_ + t] = f2bf(v);
  }
}

// ---------------- BN-affine + relu on one bf16x8 fragment ----------------
__device__ __forceinline__ bf16x8 bn_relu_frag(bf16x8 v, const float* a, const float* c, int kb){
  union { bf16x8 h; unsigned short s[8]; } u; u.h = v;
  union { float4 v4; float f[4]; } a0, a1, c0, c1;
  a0.v4 = *(const float4*)(a + kb);  a1.v4 = *(const float4*)(a + kb + 4);
  c0.v4 = *(const float4*)(c + kb);  c1.v4 = *(const float4*)(c + kb + 4);
  #pragma unroll
  for (int j = 0; j < 4; j++){
    float f0 = fmaf(a0.f[j], bf2f(u.s[j]),     c0.f[j]);
    float f1 = fmaf(a1.f[j], bf2f(u.s[j + 4]), c1.f[j]);
    u.s[j]     = f2bf(fmaxf(f0, 0.f));
    u.s[j + 4] = f2bf(fmaxf(f1, 0.f));
  }
  return u.h;
}

// ---------------- flat MFMA GEMM: no LDS, no barriers ----------------
// C[m,n] = sum_k A[m,k]*W[n,k].  Wave tile = (WM*16) x 128; both A and B fragments are
// loaded straight from global (B is L2-resident: <=192 KB). K-loop is a pure
// MFMA+VMEM stream with 1-iteration register prefetch -- no __syncthreads at all.
// Epilogue: bf16 C store + per-column sum/sumsq atomics for BN stats.
template<int K, int WM, bool HAS_AFF>
__global__ __launch_bounds__(256, 2) void gemm_flat_kernel(
    const unsigned short* __restrict__ A, const unsigned short* __restrict__ W,
    unsigned short* __restrict__ Cout, int Ntot,
    float* sumv, float* sqv, const float* aff_a, const float* aff_c)
{
  const int t    = threadIdx.x;
  const int lane = t & 63, wave = t >> 6;
  const int ln   = lane & 15, lq = lane >> 4;
  const size_t m0 = (size_t)blockIdx.x * (4*WM*16) + (size_t)wave * (WM*16);
  const int    n0 = blockIdx.y * 128;

  const unsigned short* Ap = A + (m0 + ln) * (size_t)K + lq*8;
  const unsigned short* Wp = W + (size_t)(n0 + ln) * K + lq*8;

  const f32x4 fzero = {0.f, 0.f, 0.f, 0.f};
  f32x4 acc[WM][8];
  #pragma unroll
  for (int i = 0; i < WM; i++)
    #pragma unroll
    for (int j = 0; j < 8; j++) acc[i][j] = fzero;

  bf16x8 aP[WM], bP[8], aN[WM], bN[8];
  #pragma unroll
  for (int j = 0; j < 8; j++) bP[j] = *(const bf16x8*)(Wp + (size_t)(j*16)*K);
  #pragma unroll
  for (int i = 0; i < WM; i++) aP[i] = *(const bf16x8*)(Ap + (size_t)(i*16)*K);

  #pragma unroll
  for (int kk = 0; kk < K/32; kk++){
    const int k0 = kk*32;
    if (kk + 1 < K/32){
      const int k1 = k0 + 32;
      #pragma unroll
      for (int j = 0; j < 8; j++) bN[j] = *(const bf16x8*)(Wp + (size_t)(j*16)*K + k1);
      #pragma unroll
      for (int i = 0; i < WM; i++) aN[i] = *(const bf16x8*)(Ap + (size_t)(i*16)*K + k1);
    }
    if (HAS_AFF){
      const int kb = k0 + lq*8;
      #pragma unroll
      for (int i = 0; i < WM; i++) aP[i] = bn_relu_frag(aP[i], aff_a, aff_c, kb);
    }
    #pragma unroll
    for (int i = 0; i < WM; i++)
      #pragma unroll
      for (int j = 0; j < 8; j++)
        acc[i][j] = __builtin_amdgcn_mfma_f32_16x16x32_bf16(aP[i], bP[j], acc[i][j], 0, 0, 0);
    #pragma unroll
    for (int j = 0; j < 8; j++) bP[j] = bN[j];
    #pragma unroll
    for (int i = 0; i < WM; i++) aP[i] = aN[i];
  }

  #pragma unroll
  for (int j = 0; j < 8; j++){
    int ncol = n0 + j*16 + ln;
    float s = 0.f, q = 0.f;
    #pragma unroll
    for (int i = 0; i < WM; i++){
      size_t mrow = m0 + i*16 + lq*4;
      #pragma unroll
      for (int r = 0; r < 4; r++){
        float v = acc[i][j][r];
        Cout[(mrow + r) * Ntot + ncol] = f2bf(v);
        s += v; q += v*v;
      }
    }
    s += __shfl_xor(s, 16); s += __shfl_xor(s, 32);
    q += __shfl_xor(q, 16); q += __shfl_xor(q, 32);
    if (lq == 0){
      atomicAdd(&sumv[ncol], s);
      atomicAdd(&sqv[ncol], q);
    }
  }
}

// ---------------- finalize BN: a = g*rsqrt(var+eps), c = be - mean*a ----------------
__global__ void finalize_kernel(const float* sum, const float* sq, const float* g, const float* be,
                                float* a_out, float* c_out, int C){
  int c = threadIdx.x;
  if (c < C){
    float mean = sum[c] * (1.f / M_);
    float var  = sq[c]  * (1.f / M_) - mean*mean;
    float a = g[c] * rsqrtf(var + 1e-5f);
    a_out[c] = a;
    c_out[c] = fmaf(-mean, a, be[c]);
  }
}

// ---------------- final: BN2-affine + relu + transpose to [B,128,N] fp32 ----------------
__global__ __launch_bounds__(256) void out_kernel(const unsigned short* y2, const float* a2,
                                                  const float* c2, float* out){
  __shared__ float lds[64][65];
  int t  = threadIdx.x;
  int b  = blockIdx.z;
  int n0 = blockIdx.y * 64;
  int c0 = blockIdx.x * 64;
  int cc = t & 63, tr = t >> 6;
  float a = a2[c0 + cc], cadd = c2[c0 + cc];
  #pragma unroll
  for (int ph = 0; ph < 16; ph++){
    int nr = tr + ph*4;
    unsigned short v = y2[((size_t)(b*N_ + n0 + nr)) * H2_ + c0 + cc];
    lds[nr][cc] = fmaxf(fmaf(a, bf2f(v), cadd), 0.f);
  }
  __syncthreads();
  #pragma unroll
  for (int ph = 0; ph < 16; ph++){
    int cr = tr + ph*4;
    out[((size_t)(b*H2_ + c0 + cr)) * N_ + n0 + cc] = lds[cc][cr];
  }
}

extern "C" void kernel_launch(void* const* d_in, const int* in_sizes, int n_in,
                              void* d_out, int out_size, void* d_ws, size_t ws_size,
                              hipStream_t stream){
  const float* xyz1 = (const float*)d_in[0];
  const float* xyz2 = (const float*)d_in[1];
  const float* p1   = (const float*)d_in[2];
  const float* p2   = (const float*)d_in[3];
  const float* W1   = (const float*)d_in[4];
  const float* g1   = (const float*)d_in[6];
  const float* be1  = (const float*)d_in[7];
  const float* W2   = (const float*)d_in[8];
  const float* g2   = (const float*)d_in[10];
  const float* be2  = (const float*)d_in[11];
  float* out = (float*)d_out;

  char* ws = (char*)d_ws;
  unsigned short* x    = (unsigned short*)(ws + 0);          // [65536][384] bf16   50.3 MB
  unsigned short* p2t  = (unsigned short*)(ws + 50331648);   // [8][2048][256] bf16  8.4 MB
  unsigned short* y1   = (unsigned short*)(ws + 58720256);   // [65536][256] bf16   33.6 MB
  unsigned short* y2   = (unsigned short*)(ws + 92274688);   // [65536][128] bf16   16.8 MB
  unsigned short* w1b  = (unsigned short*)(ws + 109051904);  // [256][384] bf16
  unsigned short* w2b  = (unsigned short*)(ws + 109248512);  // [128][256] bf16
  int*            idx  = (int*)(ws + 109314048);             // [65536][3] int
  float*          wgt  = (float*)(ws + 110100480);           // [65536][3] f32
  float*          stats= (float*)(ws + 110886912);           // 1536 floats
  float* sum1 = stats;        float* sq1 = stats + 256;
  float* sum2 = stats + 512;  float* sq2 = stats + 640;
  float* a1   = stats + 768;  float* c1  = stats + 1024;
  float* a2   = stats + 1280; float* c2  = stats + 1408;
  // knn partials reuse y1 region (d: 6.3 MB at +0B, i: 6.3 MB at +12.6MB; y1 written later)
  float* partd = (float*)y1;
  int*   parti = (int*)(y1 + 6291456);   // byte offset 12.58 MB into y1 region

  prep_kernel<<<384, 256, 0, stream>>>(W1, W2, w1b, w2b, stats);
  transpose_kernel<<<dim3(64, 8, 8),  256, 0, stream>>>(p2, p2t, 256, 2048, 256, 0);
  transpose_kernel<<<dim3(256, 4, 8), 256, 0, stream>>>(p1, x,   128, 8192, 384, 0);
  knn_kernel<<<dim3(32, 8, PIECES_), 256, 0, stream>>>(xyz1, xyz2, partd, parti);
  knn_merge_kernel<<<256, 256, 0, stream>>>(partd, parti, idx, wgt);
  interp_kernel<<<4096, 256, 0, stream>>>(idx, wgt, p2t, x);
  // gemm1: M=65536, N=256, K=384; wave tile 64x128 -> grid (65536/256, 256/128)
  gemm_flat_kernel<384, 4, false><<<dim3(256, 2), 256, 0, stream>>>(
      x, w1b, y1, 256, sum1, sq1, nullptr, nullptr);
  finalize_kernel<<<1, 256, 0, stream>>>(sum1, sq1, g1, be1, a1, c1, 256);
  // gemm2: M=65536, N=128, K=256; wave tile 32x128 -> grid (65536/128, 1)
  gemm_flat_kernel<256, 2, true><<<dim3(512, 1), 256, 0, stream>>>(
      y1, w2b, y2, 128, sum2, sq2, a1, c1);
  finalize_kernel<<<1, 256, 0, stream>>>(sum2, sq2, g2, be2, a2, c2, 128);
  out_kernel<<<dim3(2, 128, 8), 256, 0, stream>>>(y2, a2, c2, out);
}

// Round 8
// 301.182 us; speedup vs baseline: 1.2210x; 1.2210x over previous
//
#include <hip/hip_runtime.h>
#include <stdint.h>

#define B_ 8
#define N_ 8192
#define S_ 2048
#define C1_ 128
#define C2_ 256
#define IN_ 384
#define H1_ 256
#define H2_ 128
#define M_ (B_*N_)   // 65536 rows

typedef short bf16x8 __attribute__((ext_vector_type(8)));
typedef float f32x4 __attribute__((ext_vector_type(4)));

__device__ __forceinline__ float bf2f(unsigned short s){
  union { unsigned int u; float f; } x; x.u = ((unsigned int)s) << 16; return x.f;
}
__device__ __forceinline__ unsigned short f2bf(float f){
  union { float f; unsigned int u; } x; x.f = f;
  unsigned int u = x.u;
  unsigned int r = (u + 0x7FFFu + ((u >> 16) & 1u)) >> 16;
  return (unsigned short)r;
}

// fragment-major layout: element (m,k) of a row-major [M][K] matrix lives at
// tile (m/16, k/32) * 512 + lane-order offset, where lane=(k>>3)&3)*16+(m&15)
// holds 8 consecutive k. A wave's MFMA fragment load = base + lane*16B = 1 KB burst.
__device__ __forceinline__ size_t fragaddr(int m, int k, int K){
  return ((size_t)((m >> 4) * (K >> 5) + (k >> 5)) << 9)
       + (size_t)((((k >> 3) & 3) << 7) + ((m & 15) << 3) + (k & 7));
}

// ---------------- prep: weights -> bf16 fragment layout, zero stats ----------------
__global__ __launch_bounds__(256) void prep_kernel(const float* W1, const float* W2,
                                                   unsigned short* w1b, unsigned short* w2b,
                                                   float* stats){
  int i = blockIdx.x * 256 + threadIdx.x;
  if (i < 256*384){
    int row = i / 384, col = i - row*384;
    w1b[fragaddr(row, col, 384)] = f2bf(W1[i]);
  }
  if (i < 128*256){
    int row = i >> 8, col = i & 255;
    w2b[fragaddr(row, col, 256)] = f2bf(W2[i]);
  }
  if (i < 1536) stats[i] = 0.f;
}

// ---------------- generic transpose (p2t only): [B][R][L] f32 -> [b*L+l][R] bf16 ----------
__global__ __launch_bounds__(256) void transpose_kernel(const float* in, unsigned short* out,
                                                        int rows_in, int cols_in,
                                                        int out_stride, int out_col_off){
  __shared__ float tile[32][33];
  int b  = blockIdx.z;
  int l0 = blockIdx.x * 32, r0 = blockIdx.y * 32;
  int tx = threadIdx.x & 31, ty = threadIdx.x >> 5;
  const float* src = in + (size_t)b * rows_in * cols_in;
  #pragma unroll
  for (int rr = ty; rr < 32; rr += 8)
    tile[rr][tx] = src[(size_t)(r0 + rr) * cols_in + l0 + tx];
  __syncthreads();
  unsigned short* dst = out + (size_t)b * cols_in * out_stride;
  #pragma unroll
  for (int rr = ty; rr < 32; rr += 8)
    dst[(size_t)(l0 + rr) * out_stride + out_col_off + r0 + tx] = f2bf(tile[tx][rr]);
}

// ---------------- p1 transpose -> x fragment layout (cols 0..127 of K=384) ----------------
__global__ __launch_bounds__(256) void transpose_p1_frag_kernel(const float* in, unsigned short* x){
  __shared__ float tile[32][33];
  int b  = blockIdx.z;
  int l0 = blockIdx.x * 32, r0 = blockIdx.y * 32;   // l: point, r: channel(k)
  int tx = threadIdx.x & 31, ty = threadIdx.x >> 5;
  const float* src = in + (size_t)b * C1_ * N_;
  #pragma unroll
  for (int rr = ty; rr < 32; rr += 8)
    tile[rr][tx] = src[(size_t)(r0 + rr) * N_ + l0 + tx];
  __syncthreads();
  #pragma unroll
  for (int rr = ty; rr < 32; rr += 8){
    int g = b * N_ + l0 + rr;
    size_t a = ((size_t)((g >> 4)*12 + (r0 >> 5)) << 9)
             + (size_t)((((tx >> 3) & 3) << 7) + ((g & 15) << 3) + (tx & 7));
    x[a] = f2bf(tile[tx][rr]);
  }
}

// ---------------- KNN pass 1: packed-key top-3 per S-piece, exact-recompute tail ----------
#define PIECES_ 8
#define SPP_ (S_ / PIECES_)   // 256 -> local idx fits 8 bits

__device__ __forceinline__ void insert_k(float& k0, float& k1, float& k2, float x){
  k2 = __builtin_amdgcn_fmed3f(k1, k2, x);
  k1 = __builtin_amdgcn_fmed3f(k0, k1, x);
  k0 = fminf(k0, x);
}

__device__ __forceinline__ void insert3(float& d0, float& d1, float& d2,
                                        int& i0, int& i1, int& i2,
                                        float x, int s){
  bool b0 = x < d0, b1 = x < d1, b2 = x < d2;
  i2 = b1 ? i1 : (b2 ? s : i2);
  i1 = b0 ? i0 : (b1 ? s : i1);
  i0 = b0 ? s : i0;
  d2 = __builtin_amdgcn_fmed3f(d1, d2, x);
  d1 = __builtin_amdgcn_fmed3f(d0, d1, x);
  d0 = fminf(d0, x);
}

__global__ __launch_bounds__(256, 8) void knn_kernel(const float* xyz1, const float* xyz2,
                                                     float* partd, int* parti){
  __shared__ float4 pts[SPP_];   // 4 KB
  int b = blockIdx.y, piece = blockIdx.z;
  int n = blockIdx.x * 256 + threadIdx.x;
  int base = piece * SPP_;
  const float* x2 = xyz2 + (size_t)b * 3 * S_;
  {
    int i = threadIdx.x;
    float px = x2[base + i], py = x2[S_ + base + i], pz = x2[2*S_ + base + i];
    pts[i] = make_float4(-2.f*px, -2.f*py, -2.f*pz, px*px + py*py + pz*pz);
  }
  __syncthreads();
  const float* x1 = xyz1 + (size_t)b * 3 * N_;
  float ax = x1[n], ay = x1[N_ + n], az = x1[2*N_ + n];
  float x1sq = ax*ax + ay*ay + az*az;

  const float KINIT = __uint_as_float(0x7F000000u);
  float k[2][3];
  k[0][0]=k[0][1]=k[0][2]=KINIT;
  k[1][0]=k[1][1]=k[1][2]=KINIT;

  for (int s = 0; s < SPP_; s += 8){
    #pragma unroll
    for (int u = 0; u < 8; u++){
      float4 c = pts[s + u];
      float dd = fmaf(ax, c.x, fmaf(ay, c.y, fmaf(az, c.z, c.w + x1sq)));
      dd = fmaxf(dd, 0.f);
      float key = __uint_as_float((__float_as_uint(dd) & 0xFFFFFF00u) | (unsigned)(s + u));
      int L = u & 1;
      insert_k(k[L][0], k[L][1], k[L][2], key);
    }
  }
  float e0 = k[0][0], e1 = k[0][1], e2 = k[0][2];
  insert_k(e0, e1, e2, k[1][0]);
  insert_k(e0, e1, e2, k[1][1]);
  insert_k(e0, e1, e2, k[1][2]);

  float ed[3]; int ei[3];
  float ev[3] = {e0, e1, e2};
  #pragma unroll
  for (int j = 0; j < 3; j++){
    int li = (int)(__float_as_uint(ev[j]) & 0xFFu);
    float4 c = pts[li];
    float dd = fmaf(ax, c.x, fmaf(ay, c.y, fmaf(az, c.z, c.w + x1sq)));
    ed[j] = fmaxf(dd, 0.f);
    ei[j] = base + li;
  }

  size_t g = (size_t)b * N_ + n;
  partd[(piece*3 + 0)*(size_t)M_ + g] = ed[0];
  partd[(piece*3 + 1)*(size_t)M_ + g] = ed[1];
  partd[(piece*3 + 2)*(size_t)M_ + g] = ed[2];
  parti[(piece*3 + 0)*(size_t)M_ + g] = ei[0];
  parti[(piece*3 + 1)*(size_t)M_ + g] = ei[1];
  parti[(piece*3 + 2)*(size_t)M_ + g] = ei[2];
}

// pass 2: exact merge of 8 pieces' top-3, weights
__global__ __launch_bounds__(256) void knn_merge_kernel(const float* partd, const int* parti,
                                                        int* idx, float* wgt){
  size_t g = (size_t)blockIdx.x * 256 + threadIdx.x;
  float d0 = partd[0*(size_t)M_ + g], d1 = partd[1*(size_t)M_ + g], d2 = partd[2*(size_t)M_ + g];
  int   i0 = parti[0*(size_t)M_ + g], i1 = parti[1*(size_t)M_ + g], i2 = parti[2*(size_t)M_ + g];
  #pragma unroll
  for (int p = 1; p < PIECES_; p++)
    #pragma unroll
    for (int j = 0; j < 3; j++)
      insert3(d0, d1, d2, i0, i1, i2,
              partd[(p*3 + j)*(size_t)M_ + g], parti[(p*3 + j)*(size_t)M_ + g]);

  float r0 = 1.f/(d0 + 1e-8f), r1 = 1.f/(d1 + 1e-8f), r2 = 1.f/(d2 + 1e-8f);
  float rs = 1.f/(r0 + r1 + r2);
  idx[g*3+0] = i0; idx[g*3+1] = i1; idx[g*3+2] = i2;
  wgt[g*3+0] = r0*rs; wgt[g*3+1] = r1*rs; wgt[g*3+2] = r2*rs;
}

// ---------------- gather + interp into x frag cols 128..383 ----------------
__global__ __launch_bounds__(256) void interp_kernel(const int* idx, const float* wgt,
                                                     const unsigned short* p2t, unsigned short* x){
  int t = threadIdx.x;                 // channel 0..255 -> k = 128+t
  int base = blockIdx.x * 16;
  size_t suboff = (size_t)((((t >> 3) & 3) << 7) + (t & 7));
  for (int k = 0; k < 16; k++){
    int g = base + k;
    int b = g >> 13;
    const int*   ip = idx + (size_t)g * 3;
    const float* wp = wgt + (size_t)g * 3;
    const unsigned short* p = p2t + (size_t)b * S_ * C2_;
    float v = wp[0]*bf2f(p[(size_t)ip[0]*C2_ + t])
            + wp[1]*bf2f(p[(size_t)ip[1]*C2_ + t])
            + wp[2]*bf2f(p[(size_t)ip[2]*C2_ + t]);
    size_t a = ((size_t)((g >> 4)*12 + 4 + (t >> 5)) << 9) + suboff + (size_t)((g & 15) << 3);
    x[a] = f2bf(v);
  }
}

// ---------------- BN-affine + relu on one bf16x8 A-fragment ----------------
__device__ __forceinline__ bf16x8 bn_relu_frag(bf16x8 v, const float* a, const float* c, int kb){
  union { bf16x8 h; unsigned short s[8]; } u; u.h = v;
  union { float4 v4; float f[4]; } a0, a1, c0, c1;
  a0.v4 = *(const float4*)(a + kb);  a1.v4 = *(const float4*)(a + kb + 4);
  c0.v4 = *(const float4*)(c + kb);  c1.v4 = *(const float4*)(c + kb + 4);
  #pragma unroll
  for (int j = 0; j < 4; j++){
    float f0 = fmaf(a0.f[j], bf2f(u.s[j]),     c0.f[j]);
    float f1 = fmaf(a1.f[j], bf2f(u.s[j + 4]), c1.f[j]);
    u.s[j]     = f2bf(fmaxf(f0, 0.f));
    u.s[j + 4] = f2bf(fmaxf(f1, 0.f));
  }
  return u.h;
}

// ---------------- fragment-layout flat GEMM: no LDS, no barriers, 1KB-burst loads --------
// A and Wf are fragment-major (see fragaddr). Wave tile 64x64, block 128x128.
// OUT_FRAG: write C in fragment layout for K_next=256 (gemm1->y1); else row-major.
template<int K, bool HAS_AFF, bool OUT_FRAG>
__global__ __launch_bounds__(256, 3) void gemm_frag_kernel(
    const unsigned short* __restrict__ A, const unsigned short* __restrict__ Wf,
    unsigned short* __restrict__ Cout, int Ntot,
    float* sumv, float* sqv, const float* aff_a, const float* aff_c)
{
  constexpr int KT = K / 32;
  const int t = threadIdx.x;
  const int lane = t & 63, wave = t >> 6;
  const int ln = lane & 15, lq = lane >> 4;
  const int wm = wave >> 1, wn = wave & 1;
  const int mt0 = blockIdx.x * 8 + wm * 4;        // first of 4 m-tiles (16 rows each)
  const int n0  = blockIdx.y * 128 + wn * 64;
  const int nt0 = n0 >> 4;

  const unsigned short* Ap = A  + (((size_t)mt0 * KT) << 9) + lane * 8;
  const unsigned short* Bp = Wf + (((size_t)nt0 * KT) << 9) + lane * 8;

  const f32x4 fzero = {0.f, 0.f, 0.f, 0.f};
  f32x4 acc[4][4];
  #pragma unroll
  for (int i = 0; i < 4; i++)
    #pragma unroll
    for (int j = 0; j < 4; j++) acc[i][j] = fzero;

  bf16x8 aP[4], bP[4], aN[4], bN[4];
  #pragma unroll
  for (int i = 0; i < 4; i++) aP[i] = *(const bf16x8*)(Ap + ((size_t)(i*KT) << 9));
  #pragma unroll
  for (int j = 0; j < 4; j++) bP[j] = *(const bf16x8*)(Bp + ((size_t)(j*KT) << 9));

  #pragma unroll
  for (int kt = 0; kt < KT; kt++){
    if (kt + 1 < KT){
      #pragma unroll
      for (int i = 0; i < 4; i++) aN[i] = *(const bf16x8*)(Ap + ((size_t)(i*KT + kt + 1) << 9));
      #pragma unroll
      for (int j = 0; j < 4; j++) bN[j] = *(const bf16x8*)(Bp + ((size_t)(j*KT + kt + 1) << 9));
    }
    if (HAS_AFF){
      const int kb = kt*32 + lq*8;
      #pragma unroll
      for (int i = 0; i < 4; i++) aP[i] = bn_relu_frag(aP[i], aff_a, aff_c, kb);
    }
    #pragma unroll
    for (int i = 0; i < 4; i++)
      #pragma unroll
      for (int j = 0; j < 4; j++)
        acc[i][j] = __builtin_amdgcn_mfma_f32_16x16x32_bf16(aP[i], bP[j], acc[i][j], 0, 0, 0);
    #pragma unroll
    for (int i = 0; i < 4; i++) aP[i] = aN[i];
    #pragma unroll
    for (int j = 0; j < 4; j++) bP[j] = bN[j];
  }

  #pragma unroll
  for (int j = 0; j < 4; j++){
    int ncol = n0 + j*16 + ln;
    float s = 0.f, q = 0.f;
    #pragma unroll
    for (int i = 0; i < 4; i++){
      #pragma unroll
      for (int r = 0; r < 4; r++){
        float v = acc[i][j][r];
        if (OUT_FRAG){
          size_t a = ((size_t)((mt0 + i)*8 + (ncol >> 5)) << 9)
                   + (size_t)((((ncol >> 3) & 3) << 7) + ((lq*4 + r) << 3) + (ncol & 7));
          Cout[a] = f2bf(v);
        } else {
          Cout[((size_t)((mt0 + i)*16 + lq*4 + r)) * Ntot + ncol] = f2bf(v);
        }
        s += v; q += v*v;
      }
    }
    s += __shfl_xor(s, 16); s += __shfl_xor(s, 32);
    q += __shfl_xor(q, 16); q += __shfl_xor(q, 32);
    if (lq == 0){
      atomicAdd(&sumv[ncol], s);
      atomicAdd(&sqv[ncol], q);
    }
  }
}

// ---------------- finalize BN: a = g*rsqrt(var+eps), c = be - mean*a ----------------
__global__ void finalize_kernel(const float* sum, const float* sq, const float* g, const float* be,
                                float* a_out, float* c_out, int C){
  int c = threadIdx.x;
  if (c < C){
    float mean = sum[c] * (1.f / M_);
    float var  = sq[c]  * (1.f / M_) - mean*mean;
    float a = g[c] * rsqrtf(var + 1e-5f);
    a_out[c] = a;
    c_out[c] = fmaf(-mean, a, be[c]);
  }
}

// ---------------- final: BN2-affine + relu + transpose to [B,128,N] fp32 ----------------
__global__ __launch_bounds__(256) void out_kernel(const unsigned short* y2, const float* a2,
                                                  const float* c2, float* out){
  __shared__ float lds[64][65];
  int t  = threadIdx.x;
  int b  = blockIdx.z;
  int n0 = blockIdx.y * 64;
  int c0 = blockIdx.x * 64;
  int cc = t & 63, tr = t >> 6;
  float a = a2[c0 + cc], cadd = c2[c0 + cc];
  #pragma unroll
  for (int ph = 0; ph < 16; ph++){
    int nr = tr + ph*4;
    unsigned short v = y2[((size_t)(b*N_ + n0 + nr)) * H2_ + c0 + cc];
    lds[nr][cc] = fmaxf(fmaf(a, bf2f(v), cadd), 0.f);
  }
  __syncthreads();
  #pragma unroll
  for (int ph = 0; ph < 16; ph++){
    int cr = tr + ph*4;
    out[((size_t)(b*H2_ + c0 + cr)) * N_ + n0 + cc] = lds[cc][cr];
  }
}

extern "C" void kernel_launch(void* const* d_in, const int* in_sizes, int n_in,
                              void* d_out, int out_size, void* d_ws, size_t ws_size,
                              hipStream_t stream){
  const float* xyz1 = (const float*)d_in[0];
  const float* xyz2 = (const float*)d_in[1];
  const float* p1   = (const float*)d_in[2];
  const float* p2   = (const float*)d_in[3];
  const float* W1   = (const float*)d_in[4];
  const float* g1   = (const float*)d_in[6];
  const float* be1  = (const float*)d_in[7];
  const float* W2   = (const float*)d_in[8];
  const float* g2   = (const float*)d_in[10];
  const float* be2  = (const float*)d_in[11];
  float* out = (float*)d_out;

  char* ws = (char*)d_ws;
  unsigned short* x    = (unsigned short*)(ws + 0);          // [65536][384] bf16 frag  50.3 MB
  unsigned short* p2t  = (unsigned short*)(ws + 50331648);   // [8][2048][256] bf16 row  8.4 MB
  unsigned short* y1   = (unsigned short*)(ws + 58720256);   // [65536][256] bf16 frag  33.6 MB
  unsigned short* y2   = (unsigned short*)(ws + 92274688);   // [65536][128] bf16 row   16.8 MB
  unsigned short* w1b  = (unsigned short*)(ws + 109051904);  // [256][384] bf16 frag
  unsigned short* w2b  = (unsigned short*)(ws + 109248512);  // [128][256] bf16 frag
  int*            idx  = (int*)(ws + 109314048);             // [65536][3] int
  float*          wgt  = (float*)(ws + 110100480);           // [65536][3] f32
  float*          stats= (float*)(ws + 110886912);           // 1536 floats
  float* sum1 = stats;        float* sq1 = stats + 256;
  float* sum2 = stats + 512;  float* sq2 = stats + 640;
  float* a1   = stats + 768;  float* c1  = stats + 1024;
  float* a2   = stats + 1280; float* c2  = stats + 1408;
  // knn partials reuse y1 region (d: 6.3 MB at +0B, i: 6.3 MB at +12.6MB; y1 written later)
  float* partd = (float*)y1;
  int*   parti = (int*)(y1 + 6291456);

  prep_kernel<<<384, 256, 0, stream>>>(W1, W2, w1b, w2b, stats);
  transpose_kernel<<<dim3(64, 8, 8), 256, 0, stream>>>(p2, p2t, 256, 2048, 256, 0);
  transpose_p1_frag_kernel<<<dim3(256, 4, 8), 256, 0, stream>>>(p1, x);
  knn_kernel<<<dim3(32, 8, PIECES_), 256, 0, stream>>>(xyz1, xyz2, partd, parti);
  knn_merge_kernel<<<256, 256, 0, stream>>>(partd, parti, idx, wgt);
  interp_kernel<<<4096, 256, 0, stream>>>(idx, wgt, p2t, x);
  // gemm1: M=65536, N=256, K=384; block 128x128 -> grid (512, 2); y1 in frag layout (K=256)
  gemm_frag_kernel<384, false, true><<<dim3(512, 2), 256, 0, stream>>>(
      x, w1b, y1, 256, sum1, sq1, nullptr, nullptr);
  finalize_kernel<<<1, 256, 0, stream>>>(sum1, sq1, g1, be1, a1, c1, 256);
  // gemm2: M=65536, N=128, K=256; block 128x128 -> grid (512, 1); y2 row layout
  gemm_frag_kernel<256, true, false><<<dim3(512, 1), 256, 0, stream>>>(
      y1, w2b, y2, 128, sum2, sq2, a1, c1);
  finalize_kernel<<<1, 256, 0, stream>>>(sum2, sq2, g2, be2, a2, c2, 128);
  out_kernel<<<dim3(2, 128, 8), 256, 0, stream>>>(y2, a2, c2, out);
}

// Round 9
// 270.337 us; speedup vs baseline: 1.3603x; 1.1141x over previous
//
#include <hip/hip_runtime.h>
#include <stdint.h>

#define B_ 8
#define N_ 8192
#define S_ 2048
#define C1_ 128
#define C2_ 256
#define IN_ 384
#define H1_ 256
#define H2_ 128
#define M_ (B_*N_)   // 65536 rows

typedef short bf16x8 __attribute__((ext_vector_type(8)));
typedef float f32x4 __attribute__((ext_vector_type(4)));

__device__ __forceinline__ float bf2f(unsigned short s){
  union { unsigned int u; float f; } x; x.u = ((unsigned int)s) << 16; return x.f;
}
__device__ __forceinline__ unsigned short f2bf(float f){
  union { float f; unsigned int u; } x; x.f = f;
  unsigned int u = x.u;
  unsigned int r = (u + 0x7FFFu + ((u >> 16) & 1u)) >> 16;
  return (unsigned short)r;
}

// fragment-major layout: element (m,k) of a row-major [M][K] matrix lives at
// tile (m/16, k/32) * 512 + lane-order offset; a wave's fragment = 1 KB contiguous burst.
__device__ __forceinline__ size_t fragaddr(int m, int k, int K){
  return ((size_t)((m >> 4) * (K >> 5) + (k >> 5)) << 9)
       + (size_t)((((k >> 3) & 3) << 7) + ((m & 15) << 3) + (k & 7));
}

// async global->LDS, 16B per lane (m97's mechanism: dest is wave-uniform base + lane*16)
__device__ __forceinline__ void gload_lds16(const unsigned short* g, unsigned short* l){
  __builtin_amdgcn_global_load_lds(
      (const __attribute__((address_space(1))) unsigned int*)g,
      (__attribute__((address_space(3))) unsigned int*)l, 16, 0, 0);
}

// ---------------- prep: weights -> bf16 fragment layout, zero stats ----------------
__global__ __launch_bounds__(256) void prep_kernel(const float* W1, const float* W2,
                                                   unsigned short* w1b, unsigned short* w2b,
                                                   float* stats){
  int i = blockIdx.x * 256 + threadIdx.x;
  if (i < 256*384){
    int row = i / 384, col = i - row*384;
    w1b[fragaddr(row, col, 384)] = f2bf(W1[i]);
  }
  if (i < 128*256){
    int row = i >> 8, col = i & 255;
    w2b[fragaddr(row, col, 256)] = f2bf(W2[i]);
  }
  if (i < 1536) stats[i] = 0.f;
}

// ---------------- generic transpose (p2t only): [B][R][L] f32 -> [b*L+l][R] bf16 ----------
__global__ __launch_bounds__(256) void transpose_kernel(const float* in, unsigned short* out,
                                                        int rows_in, int cols_in,
                                                        int out_stride, int out_col_off){
  __shared__ float tile[32][33];
  int b  = blockIdx.z;
  int l0 = blockIdx.x * 32, r0 = blockIdx.y * 32;
  int tx = threadIdx.x & 31, ty = threadIdx.x >> 5;
  const float* src = in + (size_t)b * rows_in * cols_in;
  #pragma unroll
  for (int rr = ty; rr < 32; rr += 8)
    tile[rr][tx] = src[(size_t)(r0 + rr) * cols_in + l0 + tx];
  __syncthreads();
  unsigned short* dst = out + (size_t)b * cols_in * out_stride;
  #pragma unroll
  for (int rr = ty; rr < 32; rr += 8)
    dst[(size_t)(l0 + rr) * out_stride + out_col_off + r0 + tx] = f2bf(tile[tx][rr]);
}

// ---------------- p1 transpose -> x fragment layout (cols 0..127 of K=384) ----------------
__global__ __launch_bounds__(256) void transpose_p1_frag_kernel(const float* in, unsigned short* x){
  __shared__ float tile[32][33];
  int b  = blockIdx.z;
  int l0 = blockIdx.x * 32, r0 = blockIdx.y * 32;   // l: point, r: channel(k)
  int tx = threadIdx.x & 31, ty = threadIdx.x >> 5;
  const float* src = in + (size_t)b * C1_ * N_;
  #pragma unroll
  for (int rr = ty; rr < 32; rr += 8)
    tile[rr][tx] = src[(size_t)(r0 + rr) * N_ + l0 + tx];
  __syncthreads();
  #pragma unroll
  for (int rr = ty; rr < 32; rr += 8){
    int g = b * N_ + l0 + rr;
    size_t a = ((size_t)((g >> 4)*12 + (r0 >> 5)) << 9)
             + (size_t)((((tx >> 3) & 3) << 7) + ((g & 15) << 3) + (tx & 7));
    x[a] = f2bf(tile[tx][rr]);
  }
}

// ---------------- KNN pass 1: packed-key top-3 per S-piece, exact-recompute tail ----------
#define PIECES_ 8
#define SPP_ (S_ / PIECES_)   // 256 -> local idx fits 8 bits

__device__ __forceinline__ void insert_k(float& k0, float& k1, float& k2, float x){
  k2 = __builtin_amdgcn_fmed3f(k1, k2, x);
  k1 = __builtin_amdgcn_fmed3f(k0, k1, x);
  k0 = fminf(k0, x);
}

__device__ __forceinline__ void insert3(float& d0, float& d1, float& d2,
                                        int& i0, int& i1, int& i2,
                                        float x, int s){
  bool b0 = x < d0, b1 = x < d1, b2 = x < d2;
  i2 = b1 ? i1 : (b2 ? s : i2);
  i1 = b0 ? i0 : (b1 ? s : i1);
  i0 = b0 ? s : i0;
  d2 = __builtin_amdgcn_fmed3f(d1, d2, x);
  d1 = __builtin_amdgcn_fmed3f(d0, d1, x);
  d0 = fminf(d0, x);
}

__global__ __launch_bounds__(256, 8) void knn_kernel(const float* xyz1, const float* xyz2,
                                                     float* partd, int* parti){
  __shared__ float4 pts[SPP_];   // 4 KB
  int b = blockIdx.y, piece = blockIdx.z;
  int n = blockIdx.x * 256 + threadIdx.x;
  int base = piece * SPP_;
  const float* x2 = xyz2 + (size_t)b * 3 * S_;
  {
    int i = threadIdx.x;
    float px = x2[base + i], py = x2[S_ + base + i], pz = x2[2*S_ + base + i];
    pts[i] = make_float4(-2.f*px, -2.f*py, -2.f*pz, px*px + py*py + pz*pz);
  }
  __syncthreads();
  const float* x1 = xyz1 + (size_t)b * 3 * N_;
  float ax = x1[n], ay = x1[N_ + n], az = x1[2*N_ + n];
  float x1sq = ax*ax + ay*ay + az*az;

  const float KINIT = __uint_as_float(0x7F000000u);
  float k[2][3];
  k[0][0]=k[0][1]=k[0][2]=KINIT;
  k[1][0]=k[1][1]=k[1][2]=KINIT;

  for (int s = 0; s < SPP_; s += 8){
    #pragma unroll
    for (int u = 0; u < 8; u++){
      float4 c = pts[s + u];
      float dd = fmaf(ax, c.x, fmaf(ay, c.y, fmaf(az, c.z, c.w + x1sq)));
      dd = fmaxf(dd, 0.f);
      float key = __uint_as_float((__float_as_uint(dd) & 0xFFFFFF00u) | (unsigned)(s + u));
      int L = u & 1;
      insert_k(k[L][0], k[L][1], k[L][2], key);
    }
  }
  float e0 = k[0][0], e1 = k[0][1], e2 = k[0][2];
  insert_k(e0, e1, e2, k[1][0]);
  insert_k(e0, e1, e2, k[1][1]);
  insert_k(e0, e1, e2, k[1][2]);

  float ed[3]; int ei[3];
  float ev[3] = {e0, e1, e2};
  #pragma unroll
  for (int j = 0; j < 3; j++){
    int li = (int)(__float_as_uint(ev[j]) & 0xFFu);
    float4 c = pts[li];
    float dd = fmaf(ax, c.x, fmaf(ay, c.y, fmaf(az, c.z, c.w + x1sq)));
    ed[j] = fmaxf(dd, 0.f);
    ei[j] = base + li;
  }

  size_t g = (size_t)b * N_ + n;
  partd[(piece*3 + 0)*(size_t)M_ + g] = ed[0];
  partd[(piece*3 + 1)*(size_t)M_ + g] = ed[1];
  partd[(piece*3 + 2)*(size_t)M_ + g] = ed[2];
  parti[(piece*3 + 0)*(size_t)M_ + g] = ei[0];
  parti[(piece*3 + 1)*(size_t)M_ + g] = ei[1];
  parti[(piece*3 + 2)*(size_t)M_ + g] = ei[2];
}

// pass 2: exact merge of 8 pieces' top-3, weights
__global__ __launch_bounds__(256) void knn_merge_kernel(const float* partd, const int* parti,
                                                        int* idx, float* wgt){
  size_t g = (size_t)blockIdx.x * 256 + threadIdx.x;
  float d0 = partd[0*(size_t)M_ + g], d1 = partd[1*(size_t)M_ + g], d2 = partd[2*(size_t)M_ + g];
  int   i0 = parti[0*(size_t)M_ + g], i1 = parti[1*(size_t)M_ + g], i2 = parti[2*(size_t)M_ + g];
  #pragma unroll
  for (int p = 1; p < PIECES_; p++)
    #pragma unroll
    for (int j = 0; j < 3; j++)
      insert3(d0, d1, d2, i0, i1, i2,
              partd[(p*3 + j)*(size_t)M_ + g], parti[(p*3 + j)*(size_t)M_ + g]);

  float r0 = 1.f/(d0 + 1e-8f), r1 = 1.f/(d1 + 1e-8f), r2 = 1.f/(d2 + 1e-8f);
  float rs = 1.f/(r0 + r1 + r2);
  idx[g*3+0] = i0; idx[g*3+1] = i1; idx[g*3+2] = i2;
  wgt[g*3+0] = r0*rs; wgt[g*3+1] = r1*rs; wgt[g*3+2] = r2*rs;
}

// ---------------- gather + interp into x frag cols 128..383 ----------------
__global__ __launch_bounds__(256) void interp_kernel(const int* idx, const float* wgt,
                                                     const unsigned short* p2t, unsigned short* x){
  int t = threadIdx.x;                 // channel 0..255 -> k = 128+t
  int base = blockIdx.x * 16;
  size_t suboff = (size_t)((((t >> 3) & 3) << 7) + (t & 7));
  for (int k = 0; k < 16; k++){
    int g = base + k;
    int b = g >> 13;
    const int*   ip = idx + (size_t)g * 3;
    const float* wp = wgt + (size_t)g * 3;
    const unsigned short* p = p2t + (size_t)b * S_ * C2_;
    float v = wp[0]*bf2f(p[(size_t)ip[0]*C2_ + t])
            + wp[1]*bf2f(p[(size_t)ip[1]*C2_ + t])
            + wp[2]*bf2f(p[(size_t)ip[2]*C2_ + t]);
    size_t a = ((size_t)((g >> 4)*12 + 4 + (t >> 5)) << 9) + suboff + (size_t)((g & 15) << 3);
    x[a] = f2bf(v);
  }
}

// ---------------- BN-affine + relu on one bf16x8 A-fragment ----------------
__device__ __forceinline__ bf16x8 bn_relu_frag(bf16x8 v, const float* a, const float* c, int kb){
  union { bf16x8 h; unsigned short s[8]; } u; u.h = v;
  union { float4 v4; float f[4]; } a0, a1, c0, c1;
  a0.v4 = *(const float4*)(a + kb);  a1.v4 = *(const float4*)(a + kb + 4);
  c0.v4 = *(const float4*)(c + kb);  c1.v4 = *(const float4*)(c + kb + 4);
  #pragma unroll
  for (int j = 0; j < 4; j++){
    float f0 = fmaf(a0.f[j], bf2f(u.s[j]),     c0.f[j]);
    float f1 = fmaf(a1.f[j], bf2f(u.s[j + 4]), c1.f[j]);
    u.s[j]     = f2bf(fmaxf(f0, 0.f));
    u.s[j + 4] = f2bf(fmaxf(f1, 0.f));
  }
  return u.h;
}

// ---------------- m97-style MFMA GEMM on frag layouts ----------------
// 128x128 block tile, 4 waves (each 64x64 = 4x4 MFMA), BK=32.
// Staging: global_load_lds dwordx4 (async, no VGPR round-trip); LDS layout == frag layout
// so ds_read_b128 at lane*16 is the MFMA fragment. 2 barriers per K-iter (m97 structure).
// Stats: per-block LDS reduction, then 4 global atomics per block (guideline 12).
template<int K, bool HAS_AFF, bool OUT_FRAG>
__global__ __launch_bounds__(256) void gemm_lds_kernel(
    const unsigned short* __restrict__ A, const unsigned short* __restrict__ Wf,
    unsigned short* __restrict__ Cout, int Ntot,
    float* sumv, float* sqv, const float* aff_a, const float* aff_c)
{
  constexpr int KT = K / 32;
  __shared__ unsigned short smA[128*32];   // 8 KB, frag-ordered: 8 chunks of 512 shorts
  __shared__ unsigned short smB[128*32];   // 8 KB
  __shared__ float ldsStat[256];           // [0..127]=sum per col, [128..255]=sumsq

  const int t = threadIdx.x;
  const int lane = t & 63, wave = t >> 6;
  const int ln = lane & 15, lq = lane >> 4;
  const int wm = wave >> 1, wn = wave & 1;
  const int mtb = blockIdx.x * 8;          // block's first m-tile
  const int ntb = blockIdx.y * 8;          // block's first n-tile
  const int mtw = mtb + wm * 4;            // wave's first m-tile
  const int n0  = blockIdx.y * 128 + wn * 64;

  ldsStat[t] = 0.f;

  // staging pointers: wave stages chunks {2*wave, 2*wave+1} of both A and B tiles
  const int c0 = 2*wave, c1 = 2*wave + 1;
  const unsigned short* gA0 = A  + (((size_t)((mtb + c0)*KT)) << 9) + lane*8;
  const unsigned short* gA1 = A  + (((size_t)((mtb + c1)*KT)) << 9) + lane*8;
  const unsigned short* gB0 = Wf + (((size_t)((ntb + c0)*KT)) << 9) + lane*8;
  const unsigned short* gB1 = Wf + (((size_t)((ntb + c1)*KT)) << 9) + lane*8;
  unsigned short* lA0 = &smA[(c0 << 9) + lane*8];
  unsigned short* lA1 = &smA[(c1 << 9) + lane*8];
  unsigned short* lB0 = &smB[(c0 << 9) + lane*8];
  unsigned short* lB1 = &smB[(c1 << 9) + lane*8];

  const f32x4 fzero = {0.f, 0.f, 0.f, 0.f};
  f32x4 acc[4][4];
  #pragma unroll
  for (int i = 0; i < 4; i++)
    #pragma unroll
    for (int j = 0; j < 4; j++) acc[i][j] = fzero;

  for (int kt = 0; kt < KT; kt++){
    const size_t koff = (size_t)kt << 9;
    gload_lds16(gA0 + koff, lA0);
    gload_lds16(gA1 + koff, lA1);
    gload_lds16(gB0 + koff, lB0);
    gload_lds16(gB1 + koff, lB1);
    __syncthreads();                        // drains vmcnt -> LDS tiles valid

    bf16x8 af[4], bf[4];
    #pragma unroll
    for (int i = 0; i < 4; i++)
      af[i] = *(const bf16x8*)(&smA[((wm*4 + i) << 9) + lane*8]);
    #pragma unroll
    for (int j = 0; j < 4; j++)
      bf[j] = *(const bf16x8*)(&smB[((wn*4 + j) << 9) + lane*8]);
    if (HAS_AFF){
      const int kb = kt*32 + lq*8;
      #pragma unroll
      for (int i = 0; i < 4; i++) af[i] = bn_relu_frag(af[i], aff_a, aff_c, kb);
    }
    #pragma unroll
    for (int i = 0; i < 4; i++)
      #pragma unroll
      for (int j = 0; j < 4; j++)
        acc[i][j] = __builtin_amdgcn_mfma_f32_16x16x32_bf16(af[i], bf[j], acc[i][j], 0, 0, 0);
    __syncthreads();                        // all reads done before next overwrite
  }

  #pragma unroll
  for (int j = 0; j < 4; j++){
    int ncol = n0 + j*16 + ln;
    float s = 0.f, q = 0.f;
    #pragma unroll
    for (int i = 0; i < 4; i++){
      #pragma unroll
      for (int r = 0; r < 4; r++){
        float v = acc[i][j][r];
        if (OUT_FRAG){
          size_t a = ((size_t)((mtw + i)*8 + (ncol >> 5)) << 9)
                   + (size_t)((((ncol >> 3) & 3) << 7) + ((lq*4 + r) << 3) + (ncol & 7));
          Cout[a] = f2bf(v);
        } else {
          Cout[((size_t)((mtw + i)*16 + lq*4 + r)) * Ntot + ncol] = f2bf(v);
        }
        s += v; q += v*v;
      }
    }
    s += __shfl_xor(s, 16); s += __shfl_xor(s, 32);
    q += __shfl_xor(q, 16); q += __shfl_xor(q, 32);
    if (lq == 0){
      int colLocal = wn*64 + j*16 + ln;
      atomicAdd(&ldsStat[colLocal], s);
      atomicAdd(&ldsStat[128 + colLocal], q);
    }
  }
  __syncthreads();
  {
    float v = ldsStat[t];
    int col = blockIdx.y*128 + (t & 127);
    atomicAdd((t < 128 ? &sumv[col] : &sqv[col]), v);
  }
}

// ---------------- finalize BN: a = g*rsqrt(var+eps), c = be - mean*a ----------------
__global__ void finalize_kernel(const float* sum, const float* sq, const float* g, const float* be,
                                float* a_out, float* c_out, int C){
  int c = threadIdx.x;
  if (c < C){
    float mean = sum[c] * (1.f / M_);
    float var  = sq[c]  * (1.f / M_) - mean*mean;
    float a = g[c] * rsqrtf(var + 1e-5f);
    a_out[c] = a;
    c_out[c] = fmaf(-mean, a, be[c]);
  }
}

// ---------------- final: BN2-affine + relu + transpose to [B,128,N] fp32 ----------------
__global__ __launch_bounds__(256) void out_kernel(const unsigned short* y2, const float* a2,
                                                  const float* c2, float* out){
  __shared__ float lds[64][65];
  int t  = threadIdx.x;
  int b  = blockIdx.z;
  int n0 = blockIdx.y * 64;
  int c0 = blockIdx.x * 64;
  int cc = t & 63, tr = t >> 6;
  float a = a2[c0 + cc], cadd = c2[c0 + cc];
  #pragma unroll
  for (int ph = 0; ph < 16; ph++){
    int nr = tr + ph*4;
    unsigned short v = y2[((size_t)(b*N_ + n0 + nr)) * H2_ + c0 + cc];
    lds[nr][cc] = fmaxf(fmaf(a, bf2f(v), cadd), 0.f);
  }
  __syncthreads();
  #pragma unroll
  for (int ph = 0; ph < 16; ph++){
    int cr = tr + ph*4;
    out[((size_t)(b*H2_ + c0 + cr)) * N_ + n0 + cc] = lds[cc][cr];
  }
}

extern "C" void kernel_launch(void* const* d_in, const int* in_sizes, int n_in,
                              void* d_out, int out_size, void* d_ws, size_t ws_size,
                              hipStream_t stream){
  const float* xyz1 = (const float*)d_in[0];
  const float* xyz2 = (const float*)d_in[1];
  const float* p1   = (const float*)d_in[2];
  const float* p2   = (const float*)d_in[3];
  const float* W1   = (const float*)d_in[4];
  const float* g1   = (const float*)d_in[6];
  const float* be1  = (const float*)d_in[7];
  const float* W2   = (const float*)d_in[8];
  const float* g2   = (const float*)d_in[10];
  const float* be2  = (const float*)d_in[11];
  float* out = (float*)d_out;

  char* ws = (char*)d_ws;
  unsigned short* x    = (unsigned short*)(ws + 0);          // [65536][384] bf16 frag  50.3 MB
  unsigned short* p2t  = (unsigned short*)(ws + 50331648);   // [8][2048][256] bf16 row  8.4 MB
  unsigned short* y1   = (unsigned short*)(ws + 58720256);   // [65536][256] bf16 frag  33.6 MB
  unsigned short* y2   = (unsigned short*)(ws + 92274688);   // [65536][128] bf16 row   16.8 MB
  unsigned short* w1b  = (unsigned short*)(ws + 109051904);  // [256][384] bf16 frag
  unsigned short* w2b  = (unsigned short*)(ws + 109248512);  // [128][256] bf16 frag
  int*            idx  = (int*)(ws + 109314048);             // [65536][3] int
  float*          wgt  = (float*)(ws + 110100480);           // [65536][3] f32
  float*          stats= (float*)(ws + 110886912);           // 1536 floats
  float* sum1 = stats;        float* sq1 = stats + 256;
  float* sum2 = stats + 512;  float* sq2 = stats + 640;
  float* a1   = stats + 768;  float* c1  = stats + 1024;
  float* a2   = stats + 1280; float* c2  = stats + 1408;
  // knn partials reuse y1 region (d: 6.3 MB at +0B, i: 6.3 MB at +12.6MB; y1 written later)
  float* partd = (float*)y1;
  int*   parti = (int*)(y1 + 6291456);

  prep_kernel<<<384, 256, 0, stream>>>(W1, W2, w1b, w2b, stats);
  transpose_kernel<<<dim3(64, 8, 8), 256, 0, stream>>>(p2, p2t, 256, 2048, 256, 0);
  transpose_p1_frag_kernel<<<dim3(256, 4, 8), 256, 0, stream>>>(p1, x);
  knn_kernel<<<dim3(32, 8, PIECES_), 256, 0, stream>>>(xyz1, xyz2, partd, parti);
  knn_merge_kernel<<<256, 256, 0, stream>>>(partd, parti, idx, wgt);
  interp_kernel<<<4096, 256, 0, stream>>>(idx, wgt, p2t, x);
  // gemm1: M=65536, N=256, K=384; block 128x128 -> grid (512, 2); y1 in frag layout (K=256)
  gemm_lds_kernel<384, false, true><<<dim3(512, 2), 256, 0, stream>>>(
      x, w1b, y1, 256, sum1, sq1, nullptr, nullptr);
  finalize_kernel<<<1, 256, 0, stream>>>(sum1, sq1, g1, be1, a1, c1, 256);
  // gemm2: M=65536, N=128, K=256; block 128x128 -> grid (512, 1); y2 row layout
  gemm_lds_kernel<256, true, false><<<dim3(512, 1), 256, 0, stream>>>(
      y1, w2b, y2, 128, sum2, sq2, a1, c1);
  finalize_kernel<<<1, 256, 0, stream>>>(sum2, sq2, g2, be2, a2, c2, 128);
  out_kernel<<<dim3(2, 128, 8), 256, 0, stream>>>(y2, a2, c2, out);
}

// Round 10
// 267.738 us; speedup vs baseline: 1.3735x; 1.0097x over previous
//
#include <hip/hip_runtime.h>
#include <stdint.h>

#define B_ 8
#define N_ 8192
#define S_ 2048
#define C1_ 128
#define C2_ 256
#define IN_ 384
#define H1_ 256
#define H2_ 128
#define M_ (B_*N_)   // 65536 rows

typedef short bf16x8 __attribute__((ext_vector_type(8)));
typedef float f32x4 __attribute__((ext_vector_type(4)));

__device__ __forceinline__ float bf2f(unsigned short s){
  union { unsigned int u; float f; } x; x.u = ((unsigned int)s) << 16; return x.f;
}
__device__ __forceinline__ unsigned short f2bf(float f){
  union { float f; unsigned int u; } x; x.f = f;
  unsigned int u = x.u;
  unsigned int r = (u + 0x7FFFu + ((u >> 16) & 1u)) >> 16;
  return (unsigned short)r;
}

// fragment-major layout: element (m,k) of a row-major [M][K] matrix lives at
// tile (m/16, k/32) * 512 + lane-order offset; a wave's fragment = 1 KB contiguous burst.
__device__ __forceinline__ size_t fragaddr(int m, int k, int K){
  return ((size_t)((m >> 4) * (K >> 5) + (k >> 5)) << 9)
       + (size_t)((((k >> 3) & 3) << 7) + ((m & 15) << 3) + (k & 7));
}

// async global->LDS, 16B per lane (m97 mechanism: dest wave-uniform base + lane*16)
__device__ __forceinline__ void gload_lds16(const unsigned short* g, unsigned short* l){
  __builtin_amdgcn_global_load_lds(
      (const __attribute__((address_space(1))) unsigned int*)g,
      (__attribute__((address_space(3))) unsigned int*)l, 16, 0, 0);
}

// ---------------- fused prep: weights->frag, stats zero, p2 transpose, p1 transpose ------
// blockIdx.x ranges: [0,384) weights+stats; [384,4480) p2t; [4480,12672) p1->x frag.
__global__ __launch_bounds__(256) void prep_fused_kernel(const float* W1, const float* W2,
                                                         const float* p2, const float* p1,
                                                         unsigned short* w1b, unsigned short* w2b,
                                                         float* stats, unsigned short* p2t,
                                                         unsigned short* x){
  __shared__ float tile[32][33];
  int bx = blockIdx.x;
  if (bx < 384){
    int i = bx * 256 + threadIdx.x;
    if (i < 256*384){
      int row = i / 384, col = i - row*384;
      w1b[fragaddr(row, col, 384)] = f2bf(W1[i]);
    }
    if (i < 128*256){
      int row = i >> 8, col = i & 255;
      w2b[fragaddr(row, col, 256)] = f2bf(W2[i]);
    }
    if (i < 1536) stats[i] = 0.f;
    return;
  }
  int tx = threadIdx.x & 31, ty = threadIdx.x >> 5;
  if (bx < 4480){
    int id = bx - 384;
    int b = id >> 9, rem = id & 511;
    int l0 = (rem & 63) * 32, r0 = (rem >> 6) * 32;   // l: point in S, r: channel in C2
    const float* src = p2 + (size_t)b * C2_ * S_;
    #pragma unroll
    for (int rr = ty; rr < 32; rr += 8)
      tile[rr][tx] = src[(size_t)(r0 + rr) * S_ + l0 + tx];
    __syncthreads();
    unsigned short* dst = p2t + (size_t)b * S_ * C2_;
    #pragma unroll
    for (int rr = ty; rr < 32; rr += 8)
      dst[(size_t)(l0 + rr) * C2_ + r0 + tx] = f2bf(tile[tx][rr]);
    return;
  }
  {
    int id = bx - 4480;
    int b = id >> 10, rem = id & 1023;
    int l0 = (rem & 255) * 32, r0 = (rem >> 8) * 32;  // l: point in N, r: channel in C1
    const float* src = p1 + (size_t)b * C1_ * N_;
    #pragma unroll
    for (int rr = ty; rr < 32; rr += 8)
      tile[rr][tx] = src[(size_t)(r0 + rr) * N_ + l0 + tx];
    __syncthreads();
    #pragma unroll
    for (int rr = ty; rr < 32; rr += 8){
      int g = b * N_ + l0 + rr;
      size_t a = ((size_t)((g >> 4)*12 + (r0 >> 5)) << 9)
               + (size_t)((((tx >> 3) & 3) << 7) + ((g & 15) << 3) + (tx & 7));
      x[a] = f2bf(tile[tx][rr]);
    }
  }
}

// ---------------- KNN pass 1: packed-key top-3 per S-piece, exact-recompute tail ----------
#define PIECES_ 8
#define SPP_ (S_ / PIECES_)   // 256 -> local idx fits 8 bits

__device__ __forceinline__ void insert_k(float& k0, float& k1, float& k2, float x){
  k2 = __builtin_amdgcn_fmed3f(k1, k2, x);
  k1 = __builtin_amdgcn_fmed3f(k0, k1, x);
  k0 = fminf(k0, x);
}

__device__ __forceinline__ void insert3(float& d0, float& d1, float& d2,
                                        int& i0, int& i1, int& i2,
                                        float x, int s){
  bool b0 = x < d0, b1 = x < d1, b2 = x < d2;
  i2 = b1 ? i1 : (b2 ? s : i2);
  i1 = b0 ? i0 : (b1 ? s : i1);
  i0 = b0 ? s : i0;
  d2 = __builtin_amdgcn_fmed3f(d1, d2, x);
  d1 = __builtin_amdgcn_fmed3f(d0, d1, x);
  d0 = fminf(d0, x);
}

__global__ __launch_bounds__(256, 8) void knn_kernel(const float* xyz1, const float* xyz2,
                                                     float* partd, int* parti){
  __shared__ float4 pts[SPP_];   // 4 KB
  int b = blockIdx.y, piece = blockIdx.z;
  int n = blockIdx.x * 256 + threadIdx.x;
  int base = piece * SPP_;
  const float* x2 = xyz2 + (size_t)b * 3 * S_;
  {
    int i = threadIdx.x;
    float px = x2[base + i], py = x2[S_ + base + i], pz = x2[2*S_ + base + i];
    pts[i] = make_float4(-2.f*px, -2.f*py, -2.f*pz, px*px + py*py + pz*pz);
  }
  __syncthreads();
  const float* x1 = xyz1 + (size_t)b * 3 * N_;
  float ax = x1[n], ay = x1[N_ + n], az = x1[2*N_ + n];
  float x1sq = ax*ax + ay*ay + az*az;

  const float KINIT = __uint_as_float(0x7F000000u);
  float k[2][3];
  k[0][0]=k[0][1]=k[0][2]=KINIT;
  k[1][0]=k[1][1]=k[1][2]=KINIT;

  for (int s = 0; s < SPP_; s += 8){
    #pragma unroll
    for (int u = 0; u < 8; u++){
      float4 c = pts[s + u];
      float dd = fmaf(ax, c.x, fmaf(ay, c.y, fmaf(az, c.z, c.w + x1sq)));
      dd = fmaxf(dd, 0.f);
      float key = __uint_as_float((__float_as_uint(dd) & 0xFFFFFF00u) | (unsigned)(s + u));
      int L = u & 1;
      insert_k(k[L][0], k[L][1], k[L][2], key);
    }
  }
  float e0 = k[0][0], e1 = k[0][1], e2 = k[0][2];
  insert_k(e0, e1, e2, k[1][0]);
  insert_k(e0, e1, e2, k[1][1]);
  insert_k(e0, e1, e2, k[1][2]);

  float ed[3]; int ei[3];
  float ev[3] = {e0, e1, e2};
  #pragma unroll
  for (int j = 0; j < 3; j++){
    int li = (int)(__float_as_uint(ev[j]) & 0xFFu);
    float4 c = pts[li];
    float dd = fmaf(ax, c.x, fmaf(ay, c.y, fmaf(az, c.z, c.w + x1sq)));
    ed[j] = fmaxf(dd, 0.f);
    ei[j] = base + li;
  }

  size_t g = (size_t)b * N_ + n;
  partd[(piece*3 + 0)*(size_t)M_ + g] = ed[0];
  partd[(piece*3 + 1)*(size_t)M_ + g] = ed[1];
  partd[(piece*3 + 2)*(size_t)M_ + g] = ed[2];
  parti[(piece*3 + 0)*(size_t)M_ + g] = ei[0];
  parti[(piece*3 + 1)*(size_t)M_ + g] = ei[1];
  parti[(piece*3 + 2)*(size_t)M_ + g] = ei[2];
}

// ---------------- fused merge + gather/interp into x frag cols 128..383 ----------------
// threads 0..15 merge the block's 16 points' piece-partials into LDS; all 256 gather.
__global__ __launch_bounds__(256) void interp_kernel(const float* partd, const int* parti,
                                                     const unsigned short* p2t, unsigned short* x){
  __shared__ int   sidx[16][3];
  __shared__ float swgt[16][3];
  int t = threadIdx.x;
  int base = blockIdx.x * 16;
  if (t < 16){
    size_t g = (size_t)base + t;
    float d0 = partd[0*(size_t)M_ + g], d1 = partd[1*(size_t)M_ + g], d2 = partd[2*(size_t)M_ + g];
    int   i0 = parti[0*(size_t)M_ + g], i1 = parti[1*(size_t)M_ + g], i2 = parti[2*(size_t)M_ + g];
    #pragma unroll
    for (int p = 1; p < PIECES_; p++)
      #pragma unroll
      for (int j = 0; j < 3; j++)
        insert3(d0, d1, d2, i0, i1, i2,
                partd[(p*3 + j)*(size_t)M_ + g], parti[(p*3 + j)*(size_t)M_ + g]);
    float r0 = 1.f/(d0 + 1e-8f), r1 = 1.f/(d1 + 1e-8f), r2 = 1.f/(d2 + 1e-8f);
    float rs = 1.f/(r0 + r1 + r2);
    sidx[t][0] = i0; sidx[t][1] = i1; sidx[t][2] = i2;
    swgt[t][0] = r0*rs; swgt[t][1] = r1*rs; swgt[t][2] = r2*rs;
  }
  __syncthreads();
  size_t suboff = (size_t)((((t >> 3) & 3) << 7) + (t & 7));
  for (int k = 0; k < 16; k++){
    int g = base + k;
    int b = g >> 13;
    const unsigned short* p = p2t + (size_t)b * S_ * C2_;
    float v = swgt[k][0]*bf2f(p[(size_t)sidx[k][0]*C2_ + t])
            + swgt[k][1]*bf2f(p[(size_t)sidx[k][1]*C2_ + t])
            + swgt[k][2]*bf2f(p[(size_t)sidx[k][2]*C2_ + t]);
    size_t a = ((size_t)((g >> 4)*12 + 4 + (t >> 5)) << 9) + suboff + (size_t)((g & 15) << 3);
    x[a] = f2bf(v);
  }
}

// ---------------- BN-affine + relu on one bf16x8 A-fragment ----------------
__device__ __forceinline__ bf16x8 bn_relu_frag(bf16x8 v, const float* a, const float* c, int kb){
  union { bf16x8 h; unsigned short s[8]; } u; u.h = v;
  union { float4 v4; float f[4]; } a0, a1, c0, c1;
  a0.v4 = *(const float4*)(a + kb);  a1.v4 = *(const float4*)(a + kb + 4);
  c0.v4 = *(const float4*)(c + kb);  c1.v4 = *(const float4*)(c + kb + 4);
  #pragma unroll
  for (int j = 0; j < 4; j++){
    float f0 = fmaf(a0.f[j], bf2f(u.s[j]),     c0.f[j]);
    float f1 = fmaf(a1.f[j], bf2f(u.s[j + 4]), c1.f[j]);
    u.s[j]     = f2bf(fmaxf(f0, 0.f));
    u.s[j + 4] = f2bf(fmaxf(f1, 0.f));
  }
  return u.h;
}

// ---------------- m97-style MFMA GEMM, BK=64 (half the barriers of R8) ----------------
// 128x128 block tile, 4 waves (64x64 each). Per outer iter: stage 2 k-chunks of A+B via
// global_load_lds 16B bursts, 1 barrier, 2x(8 ds_read_b128 + 16 MFMA), 1 barrier.
template<int K, bool HAS_AFF, bool OUT_FRAG>
__global__ __launch_bounds__(256) void gemm_lds_kernel(
    const unsigned short* __restrict__ A, const unsigned short* __restrict__ Wf,
    unsigned short* __restrict__ Cout, int Ntot,
    float* sumv, float* sqv, const float* aff_a, const float* aff_c)
{
  constexpr int KT = K / 32;
  __shared__ unsigned short smA[128*64];   // 16 KB: [m-chunk 0..7][k-chunk 0..1][512]
  __shared__ unsigned short smB[128*64];   // 16 KB
  __shared__ float ldsStat[256];

  const int t = threadIdx.x;
  const int lane = t & 63, wave = t >> 6;
  const int ln = lane & 15, lq = lane >> 4;
  const int wm = wave >> 1, wn = wave & 1;
  const int mtb = blockIdx.x * 8;
  const int ntb = blockIdx.y * 8;
  const int mtw = mtb + wm * 4;
  const int n0  = blockIdx.y * 128 + wn * 64;

  ldsStat[t] = 0.f;

  const int c0 = 2*wave, c1 = 2*wave + 1;   // this wave's staging chunks

  const f32x4 fzero = {0.f, 0.f, 0.f, 0.f};
  f32x4 acc[4][4];
  #pragma unroll
  for (int i = 0; i < 4; i++)
    #pragma unroll
    for (int j = 0; j < 4; j++) acc[i][j] = fzero;

  for (int kk = 0; kk < KT; kk += 2){
    #pragma unroll
    for (int q = 0; q < 2; q++){
      gload_lds16(A  + (((size_t)((mtb + c0)*KT + kk + q)) << 9) + lane*8,
                  &smA[((c0*2 + q) << 9) + lane*8]);
      gload_lds16(A  + (((size_t)((mtb + c1)*KT + kk + q)) << 9) + lane*8,
                  &smA[((c1*2 + q) << 9) + lane*8]);
      gload_lds16(Wf + (((size_t)((ntb + c0)*KT + kk + q)) << 9) + lane*8,
                  &smB[((c0*2 + q) << 9) + lane*8]);
      gload_lds16(Wf + (((size_t)((ntb + c1)*KT + kk + q)) << 9) + lane*8,
                  &smB[((c1*2 + q) << 9) + lane*8]);
    }
    __syncthreads();
    #pragma unroll
    for (int q = 0; q < 2; q++){
      bf16x8 af[4], bf[4];
      #pragma unroll
      for (int i = 0; i < 4; i++)
        af[i] = *(const bf16x8*)(&smA[(((wm*4 + i)*2 + q) << 9) + lane*8]);
      #pragma unroll
      for (int j = 0; j < 4; j++)
        bf[j] = *(const bf16x8*)(&smB[(((wn*4 + j)*2 + q) << 9) + lane*8]);
      if (HAS_AFF){
        const int kb = (kk + q)*32 + lq*8;
        #pragma unroll
        for (int i = 0; i < 4; i++) af[i] = bn_relu_frag(af[i], aff_a, aff_c, kb);
      }
      #pragma unroll
      for (int i = 0; i < 4; i++)
        #pragma unroll
        for (int j = 0; j < 4; j++)
          acc[i][j] = __builtin_amdgcn_mfma_f32_16x16x32_bf16(af[i], bf[j], acc[i][j], 0, 0, 0);
    }
    __syncthreads();
  }

  #pragma unroll
  for (int j = 0; j < 4; j++){
    int ncol = n0 + j*16 + ln;
    float s = 0.f, q = 0.f;
    #pragma unroll
    for (int i = 0; i < 4; i++){
      #pragma unroll
      for (int r = 0; r < 4; r++){
        float v = acc[i][j][r];
        if (OUT_FRAG){
          size_t a = ((size_t)((mtw + i)*8 + (ncol >> 5)) << 9)
                   + (size_t)((((ncol >> 3) & 3) << 7) + ((lq*4 + r) << 3) + (ncol & 7));
          Cout[a] = f2bf(v);
        } else {
          Cout[((size_t)((mtw + i)*16 + lq*4 + r)) * Ntot + ncol] = f2bf(v);
        }
        s += v; q += v*v;
      }
    }
    s += __shfl_xor(s, 16); s += __shfl_xor(s, 32);
    q += __shfl_xor(q, 16); q += __shfl_xor(q, 32);
    if (lq == 0){
      int colLocal = wn*64 + j*16 + ln;
      atomicAdd(&ldsStat[colLocal], s);
      atomicAdd(&ldsStat[128 + colLocal], q);
    }
  }
  __syncthreads();
  {
    float v = ldsStat[t];
    int col = blockIdx.y*128 + (t & 127);
    atomicAdd((t < 128 ? &sumv[col] : &sqv[col]), v);
  }
}

// ---------------- finalize BN: a = g*rsqrt(var+eps), c = be - mean*a ----------------
__global__ void finalize_kernel(const float* sum, const float* sq, const float* g, const float* be,
                                float* a_out, float* c_out, int C){
  int c = threadIdx.x;
  if (c < C){
    float mean = sum[c] * (1.f / M_);
    float var  = sq[c]  * (1.f / M_) - mean*mean;
    float a = g[c] * rsqrtf(var + 1e-5f);
    a_out[c] = a;
    c_out[c] = fmaf(-mean, a, be[c]);
  }
}

// ---------------- final: BN2-affine + relu + transpose to [B,128,N] fp32 ----------------
__global__ __launch_bounds__(256) void out_kernel(const unsigned short* y2, const float* a2,
                                                  const float* c2, float* out){
  __shared__ float lds[64][65];
  int t  = threadIdx.x;
  int b  = blockIdx.z;
  int n0 = blockIdx.y * 64;
  int c0 = blockIdx.x * 64;
  int cc = t & 63, tr = t >> 6;
  float a = a2[c0 + cc], cadd = c2[c0 + cc];
  #pragma unroll
  for (int ph = 0; ph < 16; ph++){
    int nr = tr + ph*4;
    unsigned short v = y2[((size_t)(b*N_ + n0 + nr)) * H2_ + c0 + cc];
    lds[nr][cc] = fmaxf(fmaf(a, bf2f(v), cadd), 0.f);
  }
  __syncthreads();
  #pragma unroll
  for (int ph = 0; ph < 16; ph++){
    int cr = tr + ph*4;
    out[((size_t)(b*H2_ + c0 + cr)) * N_ + n0 + cc] = lds[cc][cr];
  }
}

extern "C" void kernel_launch(void* const* d_in, const int* in_sizes, int n_in,
                              void* d_out, int out_size, void* d_ws, size_t ws_size,
                              hipStream_t stream){
  const float* xyz1 = (const float*)d_in[0];
  const float* xyz2 = (const float*)d_in[1];
  const float* p1   = (const float*)d_in[2];
  const float* p2   = (const float*)d_in[3];
  const float* W1   = (const float*)d_in[4];
  const float* g1   = (const float*)d_in[6];
  const float* be1  = (const float*)d_in[7];
  const float* W2   = (const float*)d_in[8];
  const float* g2   = (const float*)d_in[10];
  const float* be2  = (const float*)d_in[11];
  float* out = (float*)d_out;

  char* ws = (char*)d_ws;
  unsigned short* x    = (unsigned short*)(ws + 0);          // [65536][384] bf16 frag  50.3 MB
  unsigned short* p2t  = (unsigned short*)(ws + 50331648);   // [8][2048][256] bf16 row  8.4 MB
  unsigned short* y1   = (unsigned short*)(ws + 58720256);   // [65536][256] bf16 frag  33.6 MB
  unsigned short* y2   = (unsigned short*)(ws + 92274688);   // [65536][128] bf16 row   16.8 MB
  unsigned short* w1b  = (unsigned short*)(ws + 109051904);  // [256][384] bf16 frag
  unsigned short* w2b  = (unsigned short*)(ws + 109248512);  // [128][256] bf16 frag
  float*          stats= (float*)(ws + 110886912);           // 1536 floats
  float* sum1 = stats;        float* sq1 = stats + 256;
  float* sum2 = stats + 512;  float* sq2 = stats + 640;
  float* a1   = stats + 768;  float* c1  = stats + 1024;
  float* a2   = stats + 1280; float* c2  = stats + 1408;
  // knn partials reuse y1 region (d: 6.3 MB at +0B, i: 6.3 MB at +12.6MB; y1 written later)
  float* partd = (float*)y1;
  int*   parti = (int*)(y1 + 6291456);

  prep_fused_kernel<<<12672, 256, 0, stream>>>(W1, W2, p2, p1, w1b, w2b, stats, p2t, x);
  knn_kernel<<<dim3(32, 8, PIECES_), 256, 0, stream>>>(xyz1, xyz2, partd, parti);
  interp_kernel<<<4096, 256, 0, stream>>>(partd, parti, p2t, x);
  // gemm1: M=65536, N=256, K=384; block 128x128 -> grid (512, 2); y1 in frag layout (K=256)
  gemm_lds_kernel<384, false, true><<<dim3(512, 2), 256, 0, stream>>>(
      x, w1b, y1, 256, sum1, sq1, nullptr, nullptr);
  finalize_kernel<<<1, 256, 0, stream>>>(sum1, sq1, g1, be1, a1, c1, 256);
  // gemm2: M=65536, N=128, K=256; block 128x128 -> grid (512, 1); y2 row layout
  gemm_lds_kernel<256, true, false><<<dim3(512, 1), 256, 0, stream>>>(
      y1, w2b, y2, 128, sum2, sq2, a1, c1);
  finalize_kernel<<<1, 256, 0, stream>>>(sum2, sq2, g2, be2, a2, c2, 128);
  out_kernel<<<dim3(2, 128, 8), 256, 0, stream>>>(y2, a2, c2, out);
}